// Round 12
// baseline (544.242 us; speedup 1.0000x reference)
//
#include <hip/hip_runtime.h>
#include <hip/hip_fp16.h>
#include <hip/hip_bf16.h>

// SlotAttention restructured:
//  dots = qs . x   with qs = LN(slots) @ (scale * Wq^T Wk)   (K never materialized)
//  updates folded:  gates_ih = (agg*fac) @ (Wih@Wv)^T        (V and upd never materialized)
// x = LN(inputs) fp16. fp32 accumulation. Output fp32.
// R11: 403us; tail = 15 dispatches x ~13us for ~3 GFLOP. R12: tail fused to
// 2 kernels/iter (t_g2: gates+GRU+LN, t_m2: mlp1+mlp2+residual+slotLN+qs),
// each block owns 4 rows end-to-end; staged [256][128] fp16 weight panels in
// LDS, 4x4 register tiles, shfl pair-reduce. 21 -> 12 dispatches.

#define BB 64
#define NN 4096
#define DD 256
#define NSL 8
#define NITER 3

__device__ __forceinline__ float wredsum(float v){
#pragma unroll
  for(int m=32;m;m>>=1) v += __shfl_xor(v, m, 64);
  return v;
}
__device__ __forceinline__ float2 u2f2(unsigned u){ __half2 h; __builtin_memcpy(&h,&u,4); return __half22float2(h); }
__device__ __forceinline__ float sigm(float v){ return 1.0f/(1.0f+__expf(-v)); }

union U4 { uint4 u; __half2 h[4]; };

// ---- staged-GEMM chunk machinery (shared by t_g2/t_m2; relies on local names
//      t, lane, wid, c4, ks and shared arrays Wst[256][128], pp[8][4][128]) ----
#define TG_STAGE(WSRC, LDW, C0) do{ \
  _Pragma("unroll") \
  for(int q=0;q<8;q++){ \
    int u_=q*512+t; int kk_=u_>>4, cb_=u_&15; \
    *(uint4*)&Wst[kk_][cb_*8] = *(const uint4*)((WSRC) + (size_t)kk_*(LDW) + (C0) + cb_*8); \
  } \
}while(0)

#define TG_COMPUTE(APTR, ASTR) do{ \
  float acc_[4][4]={{0,0,0,0},{0,0,0,0},{0,0,0,0},{0,0,0,0}}; \
  _Pragma("unroll") \
  for(int g_=0;g_<4;g_++){ \
    int kb_=ks*16+g_*4; \
    float av_[4][4]; \
    _Pragma("unroll") \
    for(int r_=0;r_<4;r_++){ \
      float4 a_=*(const float4*)((APTR) + r_*(ASTR) + kb_); \
      av_[r_][0]=a_.x; av_[r_][1]=a_.y; av_[r_][2]=a_.z; av_[r_][3]=a_.w; \
    } \
    _Pragma("unroll") \
    for(int k2_=0;k2_<4;k2_++){ \
      uint2 wv_=*(const uint2*)&Wst[kb_+k2_][c4*4]; \
      float2 wa_=u2f2(wv_.x), wb_=u2f2(wv_.y); \
      _Pragma("unroll") \
      for(int r_=0;r_<4;r_++){ \
        acc_[r_][0]+=av_[r_][k2_]*wa_.x; acc_[r_][1]+=av_[r_][k2_]*wa_.y; \
        acc_[r_][2]+=av_[r_][k2_]*wb_.x; acc_[r_][3]+=av_[r_][k2_]*wb_.y; \
      } \
    } \
  } \
  _Pragma("unroll") \
  for(int r_=0;r_<4;r_++){ \
    _Pragma("unroll") \
    for(int j_=0;j_<4;j_++) acc_[r_][j_] += __shfl_xor(acc_[r_][j_], 32, 64); \
  } \
  if(lane<32){ \
    _Pragma("unroll") \
    for(int r_=0;r_<4;r_++){ \
      float4 v_={acc_[r_][0],acc_[r_][1],acc_[r_][2],acc_[r_][3]}; \
      *(float4*)&pp[wid][r_][c4*4]=v_; \
    } \
  } \
}while(0)

// ---------------- merged prep: weights + slots + WC GEMM + M GEMMs + agg zero ----------------
__global__ __launch_bounds__(256) void kp_all(
    const float* __restrict__ Whh, const float* __restrict__ W1,
    const float* __restrict__ W2,  const float* __restrict__ sinit,
    const float* __restrict__ Wih, const float* __restrict__ Wv,
    const float* __restrict__ Wq,  const float* __restrict__ Wk,
    __half* __restrict__ Wg, __half* __restrict__ W1t, __half* __restrict__ W2t,
    float* __restrict__ slots, __half* __restrict__ M2h, __half* __restrict__ M2k,
    float* __restrict__ zbuf){
  int bid=blockIdx.x, t=threadIdx.x;
  if(bid<1664){
    for(int idx=bid*256+t; idx<851968; idx+=1664*256){
      if(idx<196608){ int col=idx>>8, c=idx&255; Wg[(size_t)c*1536+768+col]=__float2half(Whh[idx]); }
      else if(idx<458752){ int k=idx-196608; int col=k>>8, c=k&255; W1t[(size_t)c*1024+col]=__float2half(W1[k]); }
      else if(idx<720896){ int k=idx-458752; int col=k>>10, c=k&1023; W2t[(size_t)c*256+col]=__float2half(W2[k]); }
      else { int k=idx-720896; slots[k]=sinit[k&2047]; }
    }
  } else if(bid<2432){
    int col=bid-1664;            // 0..767
    __shared__ float wr[256];
    wr[t]=Wih[col*256+t];
    __syncthreads();
    float acc=0.f;
#pragma unroll 8
    for(int d=0;d<256;d++) acc += wr[d]*Wv[d*256+t];
    Wg[(size_t)t*1536+col]=__float2half(acc);
  } else if(bid<2688){
    int c=bid-2432;              // 0..255
    float acc=0.f;
#pragma unroll 8
    for(int d=0;d<256;d++) acc += Wq[d*256+t]*Wk[d*256+c];
    __half hv=__float2half(acc*0.0625f);
    M2h[(size_t)c*256+t]=hv;     // c-major (for k_pre)
    M2k[(size_t)t*256+c]=hv;     // K-major (for t_m2)
  } else {
    int idx=(bid-2688)*256+t;
    if(idx<394752) zbuf[idx]=0.f;
  }
}

// ---------------- x = LN(inputs) -> fp16 ----------------
__global__ __launch_bounds__(256) void k_ln_x(const float* __restrict__ in, const float* __restrict__ g,
                                              const float* __restrict__ bbv, __half* __restrict__ x){
  int row  = blockIdx.x*4 + (threadIdx.x>>6);
  int lane = threadIdx.x&63;
  const float4 v = ((const float4*)(in + (size_t)row*DD))[lane];
  float s  = v.x+v.y+v.z+v.w;
  float ss = v.x*v.x+v.y*v.y+v.z*v.z+v.w*v.w;
  s = wredsum(s); ss = wredsum(ss);
  float m = s*(1.0f/256.0f);
  float r = rsqrtf(ss*(1.0f/256.0f) - m*m + 1e-5f);
  float4 gv = ((const float4*)g)[lane];
  float4 bv = ((const float4*)bbv)[lane];
  float y0=(v.x-m)*r*gv.x+bv.x, y1=(v.y-m)*r*gv.y+bv.y;
  float y2=(v.z-m)*r*gv.z+bv.z, y3=(v.w-m)*r*gv.w+bv.w;
  __half2 h0=__floats2half2_rn(y0,y1), h1=__floats2half2_rn(y2,y3);
  uint2 u; __builtin_memcpy(&u.x,&h0,4); __builtin_memcpy(&u.y,&h1,4);
  ((uint2*)(x + (size_t)row*DD))[lane] = u;
}

// ---------------- initial qs = LN(slots) @ M (once) ----------------
__global__ __launch_bounds__(256) void k_pre(const float* __restrict__ slots, const float* __restrict__ g,
                                             const float* __restrict__ bbv, const __half* __restrict__ M2h,
                                             float* __restrict__ qs){
  int row = blockIdx.x;      // 0..511
  int t = threadIdx.x;
  __shared__ __align__(16) float sn[256];
  __shared__ float red[8];
  float v = slots[row*256 + t];
  float s = wredsum(v), ss = wredsum(v*v);
  int wid=t>>6, lane=t&63;
  if(lane==0){ red[wid]=s; red[4+wid]=ss; }
  __syncthreads();
  float S  = red[0]+red[1]+red[2]+red[3];
  float SS = red[4]+red[5]+red[6]+red[7];
  float m = S*(1.0f/256.0f);
  float r = rsqrtf(SS*(1.0f/256.0f) - m*m + 1e-5f);
  sn[t] = (v-m)*r*g[t]+bbv[t];
  __syncthreads();
  const uint4* w4 = (const uint4*)(M2h + (size_t)t*256);
  float acc=0.f;
#pragma unroll 4
  for(int kk=0;kk<32;kk++){
    U4 w; w.u=w4[kk];
#pragma unroll
    for(int q=0;q<4;q++){
      float2 f=__half22float2(w.h[q]);
      acc += sn[kk*8+2*q]*f.x + sn[kk*8+2*q+1]*f.y;
    }
  }
  qs[row*256+t]=acc;
}

// ---------------- fused attention: dots+softmax -> w -> partial agg (atomic) ----------------
__global__ __launch_bounds__(256) void k_att(const __half* __restrict__ x, const float* __restrict__ qs,
                                             float* __restrict__ aggF, float* __restrict__ wsumF){
  int b = blockIdx.x>>4;
  int t = threadIdx.x;
  size_t j = (size_t)blockIdx.x*256 + t;
  __shared__ __align__(16) float qt[256][8];
  __shared__ __align__(16) float wl[256][8];
  __shared__ __align__(16) float aggl[4][2048];
  __shared__ float wsl[4][8];
  const float* qb = qs + b*2048;
  for(int e=t;e<2048;e+=256) qt[e&255][e>>8]=qb[e];
  __syncthreads();
  const uint4* xr = (const uint4*)(x + j*DD);
  float pd[8]={0,0,0,0,0,0,0,0};
#pragma unroll 2
  for(int ch=0; ch<32; ch++){
    uint4 u = xr[ch];
    float2 f0=u2f2(u.x), f1=u2f2(u.y), f2=u2f2(u.z), f3=u2f2(u.w);
    float xv[8]={f0.x,f0.y,f1.x,f1.y,f2.x,f2.y,f3.x,f3.y};
    int c0=ch*8;
#pragma unroll
    for(int cc=0;cc<8;cc++){
      const float4* qp=(const float4*)&qt[c0+cc][0];
      float4 qa=qp[0], qc=qp[1];
      float xvv=xv[cc];
      pd[0]+=qa.x*xvv; pd[1]+=qa.y*xvv; pd[2]+=qa.z*xvv; pd[3]+=qa.w*xvv;
      pd[4]+=qc.x*xvv; pd[5]+=qc.y*xvv; pd[6]+=qc.z*xvv; pd[7]+=qc.w*xvv;
    }
  }
  float mx=pd[0];
#pragma unroll
  for(int i=1;i<8;i++) mx=fmaxf(mx,pd[i]);
  float ev[8]; float ssum=0.f;
#pragma unroll
  for(int i=0;i<8;i++){ ev[i]=__expf(pd[i]-mx); ssum+=ev[i]; }
  float inv=1.0f/ssum;
#pragma unroll
  for(int i=0;i<8;i++) wl[t][i]=ev[i]*inv+1e-5f;
  __syncthreads();
  int wid=t>>6, lane=t&63;
  float acc[8][4];
#pragma unroll
  for(int i=0;i<8;i++){ acc[i][0]=0;acc[i][1]=0;acc[i][2]=0;acc[i][3]=0; }
  float ws[8]={0,0,0,0,0,0,0,0};
  for(int r=0;r<64;r++){
    int jl = wid*64 + r;
    uint2 u = ((const uint2*)(x + ((size_t)blockIdx.x*256 + jl)*DD))[lane];
    float2 f01=u2f2(u.x), f23=u2f2(u.y);
    const float4* wp=(const float4*)&wl[jl][0];
    float4 wa=wp[0], wb_=wp[1];
    float wv[8]={wa.x,wa.y,wa.z,wa.w,wb_.x,wb_.y,wb_.z,wb_.w};
    float xv[4]={f01.x,f01.y,f23.x,f23.y};
#pragma unroll
    for(int i=0;i<8;i++){
      acc[i][0]+=wv[i]*xv[0]; acc[i][1]+=wv[i]*xv[1];
      acc[i][2]+=wv[i]*xv[2]; acc[i][3]+=wv[i]*xv[3];
      ws[i]+=wv[i];
    }
  }
#pragma unroll
  for(int i=0;i<8;i++){
    float4 st={acc[i][0],acc[i][1],acc[i][2],acc[i][3]};
    *((float4*)&aggl[wid][i*256 + lane*4])=st;
  }
  if(lane==0){
#pragma unroll
    for(int i=0;i<8;i++) wsl[wid][i]=ws[i];
  }
  __syncthreads();
  float* ab = aggF + (size_t)b*2048;
  for(int e=t;e<2048;e+=256)
    atomicAdd(&ab[e], aggl[0][e]+aggl[1][e]+aggl[2][e]+aggl[3][e]);
  if(t<8) atomicAdd(&wsumF[b*8+t], wsl[0][t]+wsl[1][t]+wsl[2][t]+wsl[3][t]);
}

// ---------------- t_g2: gates GEMM (12 chunks) + GRU + MLP pre-norm; 4 rows/block ----------------
__global__ __launch_bounds__(512) void t_g2(
    const float* __restrict__ aggF, const float* __restrict__ wsumF,
    const float* __restrict__ slots_in, const __half* __restrict__ Wg,
    const float* __restrict__ bih, const float* __restrict__ bhh,
    const float* __restrict__ lm_g, const float* __restrict__ lm_b,
    float* __restrict__ hb, float* __restrict__ ysf){
  int r0=blockIdx.x*4;
  int t=threadIdx.x, lane=t&63, wid=t>>6;
  int c4=t&31, ks=t>>5;
  __shared__ __align__(16) float Aih[4][256], Ahh[4][256];
  __shared__ __align__(16) __half Wst[256][128];   // 64 KB
  __shared__ __align__(16) float pp[8][4][128];    // 16 KB
  __shared__ __align__(16) float gl[4][1536];      // 24 KB
  __shared__ float redS[4][4], redQ[4][4];
  for(int u=t;u<1024;u+=512){
    int r=u>>8, c=u&255;
    Aih[r][c]=aggF[(size_t)(r0+r)*256+c]*(4096.0f/wsumF[r0+r]);
    Ahh[r][c]=slots_in[(size_t)(r0+r)*256+c];
  }
  __syncthreads();
  for(int ch=0; ch<12; ch++){
    TG_STAGE(Wg, 1536, ch*128);
    __syncthreads();
    const float* A = (ch<6)? &Aih[0][0] : &Ahh[0][0];
    TG_COMPUTE(A, 256);
    __syncthreads();
    {
      int r=t>>7, c=t&127, col=ch*128+c;
      float s=0.f;
#pragma unroll
      for(int w2=0;w2<8;w2++) s+=pp[w2][r][c];
      gl[r][col]=s + (col<768? bih[col] : bhh[col-768]);
    }
    __syncthreads();
  }
  // GRU + pre-norm (2 passes of 2 rows)
#pragma unroll
  for(int p=0;p<2;p++){
    int r=(t>>8)+p*2, c=t&255;
    float gir=gl[r][c], giz=gl[r][256+c], gin=gl[r][512+c];
    float ghr=gl[r][768+c], ghz=gl[r][1024+c], ghn=gl[r][1280+c];
    float hp=Ahh[r][c];
    float rr=sigm(gir+ghr), z=sigm(giz+ghz);
    float n=tanhf(gin+rr*ghn);
    float hv=(1.0f-z)*n+z*hp;
    hb[(size_t)(r0+r)*256+c]=hv;
    gl[r][c]=hv;   // stash (own slot; gir already consumed)
    float s=wredsum(hv), ss=wredsum(hv*hv);
    if(lane==0){ redS[r][wid&3]=s; redQ[r][wid&3]=ss; }
  }
  __syncthreads();
#pragma unroll
  for(int p=0;p<2;p++){
    int r=(t>>8)+p*2, c=t&255;
    float S =redS[r][0]+redS[r][1]+redS[r][2]+redS[r][3];
    float SS=redQ[r][0]+redQ[r][1]+redQ[r][2]+redQ[r][3];
    float m=S*(1.0f/256.0f);
    float rs=rsqrtf(SS*(1.0f/256.0f)-m*m+1e-5f);
    ysf[(size_t)(r0+r)*256+c]=(gl[r][c]-m)*rs*lm_g[c]+lm_b[c];
  }
}

// ---------------- t_m2: mlp1 (8) + mlp2 (8, K-split) + residual + slot-LN + qs (2); 4 rows/block ----------------
__global__ __launch_bounds__(512) void t_m2(
    const float* __restrict__ hb, const float* __restrict__ ysf,
    const __half* __restrict__ W1t, const float* __restrict__ b1,
    const __half* __restrict__ W2t, const float* __restrict__ b2,
    const float* __restrict__ ls_g, const float* __restrict__ ls_b,
    const __half* __restrict__ M2k,
    float* __restrict__ dst, float* __restrict__ qs, int last){
  int r0=blockIdx.x*4;
  int t=threadIdx.x, lane=t&63, wid=t>>6;
  int c4=t&31, ks=t>>5;
  __shared__ __align__(16) float ysl[4][256];
  __shared__ __align__(16) __half Wst[256][128];
  __shared__ __align__(16) float pp[8][4][128];
  __shared__ __align__(16) float z1[4][1024];
  __shared__ __align__(16) float osum[4][256];
  __shared__ float redS[4][4], redQ[4][4];
  for(int u=t;u<1024;u+=512){ int r=u>>8,c=u&255; ysl[r][c]=ysf[(size_t)(r0+r)*256+c]; }
  __syncthreads();
  // mlp1
  for(int ch=0;ch<8;ch++){
    TG_STAGE(W1t, 1024, ch*128);
    __syncthreads();
    TG_COMPUTE(&ysl[0][0], 256);
    __syncthreads();
    {
      int r=t>>7, c=t&127, col=ch*128+c;
      float s=0.f;
#pragma unroll
      for(int w2=0;w2<8;w2++) s+=pp[w2][r][c];
      s += b1[col];
      z1[r][col] = s>0.f? s : 0.01f*s;
    }
    __syncthreads();
  }
  // mlp2 (kc outer, cc inner)
  for(int kc=0;kc<4;kc++){
    for(int cc=0;cc<2;cc++){
      TG_STAGE(W2t + (size_t)kc*256*256, 256, cc*128);
      __syncthreads();
      TG_COMPUTE(&z1[0][kc*256], 1024);
      __syncthreads();
      {
        int r=t>>7, c=t&127;
        float s=0.f;
#pragma unroll
        for(int w2=0;w2<8;w2++) s+=pp[w2][r][c];
        if(kc==0) osum[r][cc*128+c]=s; else osum[r][cc*128+c]+=s;
      }
      __syncthreads();
    }
  }
  // residual + output (+ slot-LN stats)
#pragma unroll
  for(int p=0;p<2;p++){
    int r=(t>>8)+p*2, c=t&255;
    float sv = hb[(size_t)(r0+r)*256+c] + osum[r][c] + b2[c];
    dst[(size_t)(r0+r)*256+c]=sv;
    osum[r][c]=sv;
    if(!last){
      float s=wredsum(sv), ss=wredsum(sv*sv);
      if(lane==0){ redS[r][wid&3]=s; redQ[r][wid&3]=ss; }
    }
  }
  if(last) return;
  __syncthreads();
#pragma unroll
  for(int p=0;p<2;p++){
    int r=(t>>8)+p*2, c=t&255;
    float S =redS[r][0]+redS[r][1]+redS[r][2]+redS[r][3];
    float SS=redQ[r][0]+redQ[r][1]+redQ[r][2]+redQ[r][3];
    float m=S*(1.0f/256.0f);
    float rs=rsqrtf(SS*(1.0f/256.0f)-m*m+1e-5f);
    ysl[r][c]=(osum[r][c]-m)*rs*ls_g[c]+ls_b[c];
  }
  __syncthreads();
  // qs = ys2 @ M (2 chunks)
  for(int cc=0;cc<2;cc++){
    TG_STAGE(M2k, 256, cc*128);
    __syncthreads();
    TG_COMPUTE(&ysl[0][0], 256);
    __syncthreads();
    {
      int r=t>>7, c=t&127;
      float s=0.f;
#pragma unroll
      for(int w2=0;w2<8;w2++) s+=pp[w2][r][c];
      qs[(size_t)(r0+r)*256 + cc*128 + c]=s;
    }
    __syncthreads();
  }
}

extern "C" void kernel_launch(void* const* d_in, const int* in_sizes, int n_in,
                              void* d_out, int out_size, void* d_ws, size_t ws_size,
                              hipStream_t stream){
  const float* inputs=(const float*)d_in[0];
  const float* sinit =(const float*)d_in[1];
  const float* Wq =(const float*)d_in[2];
  const float* Wk =(const float*)d_in[3];
  const float* Wv =(const float*)d_in[4];
  const float* Wih=(const float*)d_in[5];
  const float* Whh=(const float*)d_in[6];
  const float* bih=(const float*)d_in[7];
  const float* bhh=(const float*)d_in[8];
  const float* lin_g=(const float*)d_in[9];
  const float* lin_b=(const float*)d_in[10];
  const float* ls_g=(const float*)d_in[11];
  const float* ls_b=(const float*)d_in[12];
  const float* lm_g=(const float*)d_in[13];
  const float* lm_b=(const float*)d_in[14];
  const float* W1=(const float*)d_in[15];
  const float* b1=(const float*)d_in[16];
  const float* W2=(const float*)d_in[17];
  const float* b2=(const float*)d_in[18];

  char* w=(char*)d_ws;
  __half* x    =(__half*)w; w += (size_t)BB*NN*DD*2;        // 134.2 MB
  float* qs    =(float*)w;  w += 512*256*4;
  float* slots =(float*)w;  w += 512*256*4;
  __half* M2h  =(__half*)w; w += 256*256*2;
  __half* M2k  =(__half*)w; w += 256*256*2;
  __half* Wg   =(__half*)w; w += 256*1536*2;
  __half* W1t  =(__half*)w; w += 256*1024*2;
  __half* W2t  =(__half*)w; w += 1024*256*2;
  float* hb    =(float*)w;  w += 512*256*4;
  float* ysf   =(float*)w;  w += 512*256*4;
  float* aggZ  =(float*)w;  w += (size_t)(3*512*256 + 3*512)*4;

  float* aggF[3]; float* wsumF[3];
  for(int i=0;i<3;i++){ aggF[i]=aggZ + (size_t)i*512*256; wsumF[i]=aggZ + (size_t)3*512*256 + (size_t)i*512; }

  hipLaunchKernelGGL(kp_all, dim3(4230), dim3(256), 0, stream,
                     Whh, W1, W2, sinit, Wih, Wv, Wq, Wk,
                     Wg, W1t, W2t, slots, M2h, M2k, aggZ);
  hipLaunchKernelGGL(k_ln_x, dim3(65536),dim3(256), 0, stream, inputs, lin_g, lin_b, x);
  hipLaunchKernelGGL(k_pre,  dim3(512),  dim3(256), 0, stream, slots, ls_g, ls_b, M2h, qs);
  for(int it=0; it<NITER; ++it){
    int last = (it==NITER-1);
    float* dst = last ? (float*)d_out : slots;
    hipLaunchKernelGGL(k_att, dim3(1024), dim3(256), 0, stream, x, qs, aggF[it], wsumF[it]);
    hipLaunchKernelGGL(t_g2,  dim3(128),  dim3(512), 0, stream, aggF[it], wsumF[it], slots, Wg,
                       bih, bhh, lm_g, lm_b, hb, ysf);
    hipLaunchKernelGGL(t_m2,  dim3(128),  dim3(512), 0, stream, hb, ysf, W1t, b1, W2t, b2,
                       ls_g, ls_b, M2k, dst, qs, last);
  }
}